// Round 3
// baseline (400.693 us; speedup 1.0000x reference)
//
#include <hip/hip_runtime.h>

#define NHEADS 12
#define SEQ    1024
#define BATCH  4
#define HDIM   768
#define DHEAD  64
#define BH_TOT 48
#define EPSN   1e-6f

typedef __attribute__((ext_vector_type(8))) short    bf8;  // 8 bf16 (4 VGPRs) MFMA A/B frag
typedef __attribute__((ext_vector_type(4))) short    s4;   // 4 bf16 packed
typedef __attribute__((ext_vector_type(4))) float    fx4;  // MFMA C/D frag / float4
typedef __attribute__((ext_vector_type(4))) _Float16 h4;   // 4 f16 (2 VGPRs) 16x16x16 frag

#define SZT 3145728u   // 48*1024*64 elements (one head-split tensor)

__device__ __forceinline__ float bf2f(unsigned short h) {
  union { unsigned int u; float f; } v; v.u = ((unsigned int)h) << 16; return v.f;
}
__device__ __forceinline__ unsigned short f2bf(float f) {
  union { float f; unsigned int u; } v; v.f = f;
  unsigned int u = v.u;
  return (unsigned short)((u + 0x7FFFu + ((u >> 16) & 1u)) >> 16);
}

// async global->LDS, 16B per lane; LDS dest must be wave-uniform base + lane*16.
typedef __attribute__((address_space(3))) unsigned int lds_u32;
typedef __attribute__((address_space(1))) const unsigned int glb_u32;
__device__ __forceinline__ void gld16(const unsigned short* g, unsigned short* l) {
  __builtin_amdgcn_global_load_lds((glb_u32*)g, (lds_u32*)l, 16, 0, 0);
}

// ---------------------------------------------------------------------------
// One-shot f32 -> bf16 conversion of X (hs,te,se) and W (q,k,v,t,s) into ws.
// Layout (ushort units): hsb@5SZ teb@6SZ seb@7SZ  W[z]@8SZ + z*589824
// ---------------------------------------------------------------------------
__global__ void convert_kernel(const float* __restrict__ hs, const float* __restrict__ te,
                               const float* __restrict__ se,
                               const float* __restrict__ Wq, const float* __restrict__ Wk,
                               const float* __restrict__ Wv, const float* __restrict__ Wt,
                               const float* __restrict__ Ws2,
                               unsigned short* __restrict__ ws)
{
  const int z = blockIdx.y;
  const float* src;
  unsigned short* dst;
  int n;
  if (z < 3) {
    src = (z == 0) ? hs : (z == 1) ? te : se;
    dst = ws + (size_t)(5 + z) * SZT;
    n = 3145728;
  } else {
    src = (z == 3) ? Wq : (z == 4) ? Wk : (z == 5) ? Wv : (z == 6) ? Wt : Ws2;
    dst = ws + (size_t)8 * SZT + (size_t)(z - 3) * 589824;
    n = 589824;
  }
  const int base = (blockIdx.x * 256 + threadIdx.x) * 8;
  if (base >= n) return;
  const fx4 a = *(const fx4*)(src + base);
  const fx4 b = *(const fx4*)(src + base + 4);
  bf8 o;
#pragma unroll
  for (int j = 0; j < 4; ++j) { o[j] = (short)f2bf(a[j]); o[4 + j] = (short)f2bf(b[j]); }
  *(bf8*)(dst + base) = o;
}

// ---------------------------------------------------------------------------
// Projection GEMM (bf16 in, m97-style global_load_lds staging):
// out = X[4096,768] @ W[768,768]^T + b, head-split.
// z: 0=Q 1=K 2=V(f16, transposed Vt[bh*64+d][1024]) 3=T 4=S
// Outputs: Qb@0 Kb@SZ Tb@2SZ Sb@3SZ Vt@4SZ (ushort units)
// ---------------------------------------------------------------------------
__global__ __launch_bounds__(256, 2)
void proj_kernel(unsigned short* __restrict__ ws,
                 const float* __restrict__ bq, const float* __restrict__ bk,
                 const float* __restrict__ bv, const float* __restrict__ bt,
                 const float* __restrict__ bs)
{
  __shared__ unsigned short Xs[128 * 32];
  __shared__ unsigned short Ys[128 * 32];

  const int z = blockIdx.z;
  const unsigned short* X = ws + (size_t)5 * SZT + (size_t)((z < 3) ? 0 : (z - 2)) * SZT;
  const unsigned short* W = ws + (size_t)8 * SZT + (size_t)z * 589824;
  const float* bias = (z == 0) ? bq : (z == 1) ? bk : (z == 2) ? bv : (z == 3) ? bt : bs;
  unsigned short* out = ws + (size_t)((z < 2) ? z : (z == 2) ? 4 : (z == 3) ? 2 : 3) * SZT;

  const int tid   = threadIdx.x;
  const int lane  = tid & 63;
  const int wid   = tid >> 6;
  const int wm    = wid >> 1, wn = wid & 1;
  const int colid = lane & 15, quad = lane >> 4;
  const int m0 = blockIdx.y * 128, n0 = blockIdx.x * 128;

  fx4 acc[4][4];
#pragma unroll
  for (int i = 0; i < 4; ++i)
#pragma unroll
    for (int j = 0; j < 4; ++j) acc[i][j] = (fx4){0.f, 0.f, 0.f, 0.f};

  for (int kt = 0; kt < HDIM; kt += 32) {
    __syncthreads();                         // prior ds_reads done before overwrite
#pragma unroll
    for (int i = 0; i < 2; ++i) {
      const int slot = i * 256 + tid;        // 0..511, 16B each; lds = base + lane*16
      const int row = slot >> 2, ch = slot & 3;
      gld16(X + (m0 + row) * HDIM + kt + ch * 8, Xs + slot * 8);
      gld16(W + (n0 + row) * HDIM + kt + ch * 8, Ys + slot * 8);
    }
    __syncthreads();                         // vmcnt(0) drain inserted by compiler

    bf8 af[4], bfr[4];
#pragma unroll
    for (int i = 0; i < 4; ++i)
      af[i] = *(const bf8*)(Xs + (wm * 64 + i * 16 + colid) * 32 + quad * 8);
#pragma unroll
    for (int j = 0; j < 4; ++j)
      bfr[j] = *(const bf8*)(Ys + (wn * 64 + j * 16 + colid) * 32 + quad * 8);
#pragma unroll
    for (int i = 0; i < 4; ++i)
#pragma unroll
      for (int j = 0; j < 4; ++j)
        acc[i][j] = __builtin_amdgcn_mfma_f32_16x16x32_bf16(af[i], bfr[j], acc[i][j], 0, 0, 0);
  }

  if (z != 2) {
#pragma unroll
    for (int i = 0; i < 4; ++i) {
      const int r0 = m0 + wm * 64 + i * 16 + quad * 4;
      const int bb = r0 >> 10, s0 = r0 & 1023;
#pragma unroll
      for (int j = 0; j < 4; ++j) {
        const int c = n0 + wn * 64 + j * 16 + colid;
        const int h = c >> 6, d = c & 63;
        const float bvl = bias[c];
        unsigned short* op = out + (((bb * NHEADS + h) * SEQ + s0) * DHEAD + d);
#pragma unroll
        for (int reg = 0; reg < 4; ++reg)
          op[reg * DHEAD] = f2bf(acc[i][j][reg] + bvl);
      }
    }
  } else {
    // V -> f16, transposed: Vt[(bh*64+d)*1024 + s], 4 consecutive s per 8B store.
#pragma unroll
    for (int i = 0; i < 4; ++i) {
      const int r0 = m0 + wm * 64 + i * 16 + quad * 4;
      const int bb = r0 >> 10, s0 = r0 & 1023;
#pragma unroll
      for (int j = 0; j < 4; ++j) {
        const int c = n0 + wn * 64 + j * 16 + colid;
        const int h = c >> 6, d = c & 63;
        const float bvl = bias[c];
        h4 pk;
#pragma unroll
        for (int reg = 0; reg < 4; ++reg)
          pk[reg] = (_Float16)(acc[i][j][reg] + bvl);
        *(h4*)(void*)(out + ((size_t)((bb * NHEADS + h) * DHEAD + d)) * SEQ + s0) = pk;
      }
    }
  }
}

// ---------------------------------------------------------------------------
// Flash attention pass 1, split-K (2 splits of 512 keys), transposed scores.
// One wave per 16 q-rows; scores^T C-layout => per-lane softmax for one q
// (2 shfl instead of 32), P regs feed 16x16x16_f16 PV MFMA directly (no LDS).
// rs (query-side norm scale) fused from T/S B-frags.
// Partials: Opart bf16 @5SZ (2 splits x SZ), ml float2 @7SZ.
// ---------------------------------------------------------------------------
__global__ __launch_bounds__(256, 4)
void attn1_kernel(const unsigned short* __restrict__ ws,
                  const float* __restrict__ maskb)
{
  __shared__ float Msh[512];

  const unsigned short* Qb  = ws;
  const unsigned short* Kb  = ws + (size_t)1 * SZT;
  const unsigned short* Tb  = ws + (size_t)2 * SZT;
  const unsigned short* Sb  = ws + (size_t)3 * SZT;
  const _Float16*       Vtf = (const _Float16*)(ws + (size_t)4 * SZT);
  unsigned short* Opart = (unsigned short*)ws + (size_t)5 * SZT;
  float2* mlp = (float2*)(ws + (size_t)7 * SZT);

  const int tid   = threadIdx.x;
  const int lane  = tid & 63;
  const int w     = tid >> 6;
  const int colid = lane & 15, quad = lane >> 4;
  const int bh = blockIdx.z;
  const int b  = bh / NHEADS;
  const int ks = blockIdx.y;
  const int q0 = blockIdx.x * 64 + w * 16;
  const int base_h = bh * SEQ * DHEAD;

  Msh[tid]       = maskb[b * SEQ + ks * 512 + tid];
  Msh[tid + 256] = maskb[b * SEQ + ks * 512 + 256 + tid];
  __syncthreads();

  // Invariant query-side B-frags: lane holds B[k=quad*8+j][n=colid] = Q[q0+colid][d]
  bf8 bqf[2], btf[2], bsf[2];
  {
    const int row = q0 + colid;
    const unsigned short* qp = Qb + base_h + row * 64 + quad * 8;
    const unsigned short* tp = Tb + base_h + row * 64 + quad * 8;
    const unsigned short* sp = Sb + base_h + row * 64 + quad * 8;
    bqf[0] = *(const bf8*)qp;  bqf[1] = *(const bf8*)(qp + 32);
    btf[0] = *(const bf8*)tp;  btf[1] = *(const bf8*)(tp + 32);
    bsf[0] = *(const bf8*)sp;  bsf[1] = *(const bf8*)(sp + 32);
  }

  // Fused per-query scale: rs = 1/((|T_q|+eps)(|S_q|+eps)*8); lives at q=colid lanes.
  float rs;
  {
    float t2 = 0.f, s2 = 0.f;
#pragma unroll
    for (int fr = 0; fr < 2; ++fr)
#pragma unroll
      for (int j = 0; j < 8; ++j) {
        const float tv = bf2f((unsigned short)btf[fr][j]);
        const float sv2 = bf2f((unsigned short)bsf[fr][j]);
        t2 += tv * tv; s2 += sv2 * sv2;
      }
    t2 += __shfl_xor(t2, 16); t2 += __shfl_xor(t2, 32);
    s2 += __shfl_xor(s2, 16); s2 += __shfl_xor(s2, 32);
    rs = 1.0f / ((sqrtf(t2) + EPSN) * (sqrtf(s2) + EPSN) * 8.0f);
  }

  float m_ = -3.0e38f, l_ = 0.f;
  fx4 o[4];
#pragma unroll
  for (int fd = 0; fd < 4; ++fd) o[fd] = (fx4){0.f, 0.f, 0.f, 0.f};
  const fx4 zero = (fx4){0.f, 0.f, 0.f, 0.f};

  const int k_lo = ks * 512;
  for (int kb = k_lo; kb < k_lo + 512; kb += 64) {
    // scores^T: A = K/T/S key rows, B = query frags. C[key=quad*4+reg][q=colid].
    float sv[4][4];
#pragma unroll
    for (int f = 0; f < 4; ++f) {
      const int key = kb + f * 16 + colid;
      const unsigned short* kp  = Kb + base_h + key * 64 + quad * 8;
      const unsigned short* tp  = Tb + base_h + key * 64 + quad * 8;
      const unsigned short* spp = Sb + base_h + key * 64 + quad * 8;
      const bf8 ak0 = *(const bf8*)kp,  ak1 = *(const bf8*)(kp + 32);
      const bf8 at0 = *(const bf8*)tp,  at1 = *(const bf8*)(tp + 32);
      const bf8 as0 = *(const bf8*)spp, as1 = *(const bf8*)(spp + 32);
      fx4 ab = __builtin_amdgcn_mfma_f32_16x16x32_bf16(ak0, bqf[0], zero, 0, 0, 0);
      ab = __builtin_amdgcn_mfma_f32_16x16x32_bf16(ak1, bqf[1], ab, 0, 0, 0);
      fx4 tt = __builtin_amdgcn_mfma_f32_16x16x32_bf16(at0, btf[0], zero, 0, 0, 0);
      tt = __builtin_amdgcn_mfma_f32_16x16x32_bf16(at1, btf[1], tt, 0, 0, 0);
      fx4 ss = __builtin_amdgcn_mfma_f32_16x16x32_bf16(as0, bsf[0], zero, 0, 0, 0);
      ss = __builtin_amdgcn_mfma_f32_16x16x32_bf16(as1, bsf[1], ss, 0, 0, 0);
      const fx4 mk4 = *(const fx4*)&Msh[(kb - k_lo) + f * 16 + quad * 4];
#pragma unroll
      for (int reg = 0; reg < 4; ++reg)
        sv[f][reg] = ab[reg] * tt[reg] * ss[reg] * rs + mk4[reg];
    }

    // Per-lane softmax for q=colid: 16 in-lane values + 2-shfl cross-quad reduce.
    float bm = sv[0][0];
#pragma unroll
    for (int f = 0; f < 4; ++f)
#pragma unroll
      for (int reg = 0; reg < 4; ++reg) bm = fmaxf(bm, sv[f][reg]);
    bm = fmaxf(bm, __shfl_xor(bm, 16));
    bm = fmaxf(bm, __shfl_xor(bm, 32));
    const float mn = fmaxf(m_, bm);
    const float alpha = __expf(m_ - mn);
    float rsum = 0.f;
    h4 pa[4];
#pragma unroll
    for (int f = 0; f < 4; ++f)
#pragma unroll
      for (int reg = 0; reg < 4; ++reg) {
        const float p = __expf(sv[f][reg] - mn);
        rsum += p;
        pa[f][reg] = (_Float16)p;
      }
    rsum += __shfl_xor(rsum, 16);
    rsum += __shfl_xor(rsum, 32);
    l_ = l_ * alpha + rsum;
    m_ = mn;

    // O rows are q=quad*4+reg: fetch their alpha from lanes 0..15 (colid==row).
    float ar[4];
#pragma unroll
    for (int reg = 0; reg < 4; ++reg) ar[reg] = __shfl(alpha, quad * 4 + reg);
#pragma unroll
    for (int fd = 0; fd < 4; ++fd)
#pragma unroll
      for (int reg = 0; reg < 4; ++reg) o[fd][reg] *= ar[reg];

    // O += P.V : P regs ARE the 16x16x16 A-frag (m=q=colid, k=quad*4+reg).
#pragma unroll
    for (int f = 0; f < 4; ++f)
#pragma unroll
      for (int fd = 0; fd < 4; ++fd) {
        const h4 bv = *(const h4*)(Vtf + (size_t)(bh * DHEAD + fd * 16 + colid) * SEQ
                                       + kb + f * 16 + quad * 4);
        o[fd] = __builtin_amdgcn_mfma_f32_16x16x16f16(pa[f], bv, o[fd], 0, 0, 0);
      }
  }

  // Partial store. O C-layout: row(q_local)=quad*4+reg, col(d)=fd*16+colid.
  const int rowg = bh * SEQ + blockIdx.x * 64 + w * 16;   // global (bh,s) row
  unsigned short* ob = Opart + (size_t)ks * SZT;
#pragma unroll
  for (int reg = 0; reg < 4; ++reg) {
    const int qr = rowg + quad * 4 + reg;
#pragma unroll
    for (int fd = 0; fd < 4; ++fd)
      ob[(size_t)qr * 64 + fd * 16 + colid] = f2bf(o[fd][reg]);
  }
  if (quad == 0)
    mlp[(size_t)ks * (BH_TOT * SEQ) + rowg + colid] = make_float2(m_, l_);
}

// ---------------------------------------------------------------------------
// Split-K combine: out[b,s,h*64+d] = sum_i w_i O_i / sum_i w_i l_i, w_i=e^{m_i-M}
// ---------------------------------------------------------------------------
__global__ void combine_kernel(const unsigned short* __restrict__ ws,
                               float* __restrict__ outb)
{
  const unsigned short* Opart = ws + (size_t)5 * SZT;
  const float2* mlp = (const float2*)(ws + (size_t)7 * SZT);
  const int gid = blockIdx.x * 256 + threadIdx.x;   // 48*1024*16 threads
  const int row = gid >> 4;                          // bh*1024 + s
  const int dq  = (gid & 15) << 2;
  const float2 ml0 = mlp[row];
  const float2 ml1 = mlp[BH_TOT * SEQ + row];
  const float M = fmaxf(ml0.x, ml1.x);
  const float w0 = __expf(ml0.x - M), w1 = __expf(ml1.x - M);
  const float inv = 1.0f / (w0 * ml0.y + w1 * ml1.y);
  const s4 a0 = *(const s4*)(Opart + (size_t)row * 64 + dq);
  const s4 a1 = *(const s4*)(Opart + (size_t)SZT + (size_t)row * 64 + dq);
  const int bh = row >> 10, s = row & 1023;
  const int bb = bh / NHEADS, h = bh - bb * NHEADS;
  fx4 r;
#pragma unroll
  for (int j = 0; j < 4; ++j)
    r[j] = (w0 * bf2f((unsigned short)a0[j]) + w1 * bf2f((unsigned short)a1[j])) * inv;
  *(fx4*)(outb + (size_t)(bb * SEQ + s) * HDIM + h * DHEAD + dq) = r;
}

extern "C" void kernel_launch(void* const* d_in, const int* in_sizes, int n_in,
                              void* d_out, int out_size, void* d_ws, size_t ws_size,
                              hipStream_t stream)
{
  (void)in_sizes; (void)n_in; (void)out_size; (void)ws_size;
  const float* hs   = (const float*)d_in[0];
  const float* te   = (const float*)d_in[1];
  const float* se   = (const float*)d_in[2];
  const float* mask = (const float*)d_in[3];
  const float* Wq   = (const float*)d_in[4];
  const float* bq   = (const float*)d_in[5];
  const float* Wk   = (const float*)d_in[6];
  const float* bk   = (const float*)d_in[7];
  const float* Wv   = (const float*)d_in[8];
  const float* bv   = (const float*)d_in[9];
  const float* Wt   = (const float*)d_in[10];
  const float* bt   = (const float*)d_in[11];
  const float* Wsp  = (const float*)d_in[12];
  const float* bsp  = (const float*)d_in[13];
  float* out = (float*)d_out;
  unsigned short* ws = (unsigned short*)d_ws;

  // ws layout (ushort units): Qb@0 Kb@1SZ Tb@2SZ Sb@3SZ Vt(f16)@4SZ
  // convert-phase: hsb@5SZ teb@6SZ seb@7SZ W[5]@8SZ+z*589824   (dead after proj)
  // attn-phase (aliases convert region): Opart@5SZ (2 x SZ), ml(float2)@7SZ
  convert_kernel<<<dim3(1536, 8), 256, 0, stream>>>(hs, te, se, Wq, Wk, Wv, Wt, Wsp, ws);
  proj_kernel<<<dim3(6, 32, 5), 256, 0, stream>>>(ws, bq, bk, bv, bt, bsp);
  attn1_kernel<<<dim3(16, 2, BH_TOT), 256, 0, stream>>>(ws, mask);
  combine_kernel<<<dim3(BH_TOT * SEQ * 16 / 256), 256, 0, stream>>>(ws, out);
}

// Round 4
// 330.850 us; speedup vs baseline: 1.2111x; 1.2111x over previous
//
#include <hip/hip_runtime.h>

#define NHEADS 12
#define SEQ    1024
#define HDIM   768
#define DHEAD  64
#define BH_TOT 48
#define EPSN   1e-6f

typedef __attribute__((ext_vector_type(8))) short    bf8;  // 8 bf16 (4 VGPRs) MFMA A/B frag
typedef __attribute__((ext_vector_type(4))) float    fx4;  // MFMA C/D frag / float4
typedef __attribute__((ext_vector_type(4))) _Float16 h4;   // 4 f16 (2 VGPRs) 16x16x16 frag

#define SZT 3145728u   // 48*1024*64 elements (one head-split tensor)

__device__ __forceinline__ float bf2f(unsigned short h) {
  union { unsigned int u; float f; } v; v.u = ((unsigned int)h) << 16; return v.f;
}
__device__ __forceinline__ unsigned short f2bf(float f) {
  union { float f; unsigned int u; } v; v.f = f;
  unsigned int u = v.u;
  return (unsigned short)((u + 0x7FFFu + ((u >> 16) & 1u)) >> 16);
}

// async global->LDS, 16B per lane; LDS dest = wave-uniform base + lane*16.
typedef __attribute__((address_space(3))) unsigned int lds_u32;
typedef __attribute__((address_space(1))) const unsigned int glb_u32;
__device__ __forceinline__ void gld16(const unsigned short* g, unsigned short* l) {
  __builtin_amdgcn_global_load_lds((glb_u32*)g, (lds_u32*)l, 16, 0, 0);
}

// ---------------------------------------------------------------------------
// One-shot f32 -> bf16 conversion of X (hs,te,se) and W (q,k,v,t,s) into ws.
// Layout (ushort units): hsb@5SZ teb@6SZ seb@7SZ  W[z]@8SZ + z*589824
// ---------------------------------------------------------------------------
__global__ void convert_kernel(const float* __restrict__ hs, const float* __restrict__ te,
                               const float* __restrict__ se,
                               const float* __restrict__ Wq, const float* __restrict__ Wk,
                               const float* __restrict__ Wv, const float* __restrict__ Wt,
                               const float* __restrict__ Ws2,
                               unsigned short* __restrict__ ws)
{
  const int z = blockIdx.y;
  const float* src;
  unsigned short* dst;
  int n;
  if (z < 3) {
    src = (z == 0) ? hs : (z == 1) ? te : se;
    dst = ws + (size_t)(5 + z) * SZT;
    n = 3145728;
  } else {
    src = (z == 3) ? Wq : (z == 4) ? Wk : (z == 5) ? Wv : (z == 6) ? Wt : Ws2;
    dst = ws + (size_t)8 * SZT + (size_t)(z - 3) * 589824;
    n = 589824;
  }
  const int base = (blockIdx.x * 256 + threadIdx.x) * 8;
  if (base >= n) return;
  const fx4 a = *(const fx4*)(src + base);
  const fx4 b = *(const fx4*)(src + base + 4);
  bf8 o;
#pragma unroll
  for (int j = 0; j < 4; ++j) { o[j] = (short)f2bf(a[j]); o[4 + j] = (short)f2bf(b[j]); }
  *(bf8*)(dst + base) = o;
}

// ---------------------------------------------------------------------------
// Projection GEMM (bf16 in): out = X[4096,768] @ W[768,768]^T + b, head-split.
// Double-buffered LDS staging via global_load_lds, ONE barrier per K-tile:
// after barrier issue tile k+1 staging, compute tile k => latency hidden.
// z: 0=Q 1=K 2=V(f16, transposed Vt[bh*64+d][1024]) 3=T 4=S
// ---------------------------------------------------------------------------
__global__ __launch_bounds__(256, 3)
void proj_kernel(unsigned short* __restrict__ ws,
                 const float* __restrict__ bq, const float* __restrict__ bk,
                 const float* __restrict__ bv, const float* __restrict__ bt,
                 const float* __restrict__ bs)
{
  __shared__ unsigned short Xs[2][4096];
  __shared__ unsigned short Ys[2][4096];

  const int z = blockIdx.z;
  const unsigned short* X = ws + (size_t)5 * SZT + (size_t)((z < 3) ? 0 : (z - 2)) * SZT;
  const unsigned short* W = ws + (size_t)8 * SZT + (size_t)z * 589824;
  const float* bias = (z == 0) ? bq : (z == 1) ? bk : (z == 2) ? bv : (z == 3) ? bt : bs;
  unsigned short* out = ws + (size_t)((z < 2) ? z : (z == 2) ? 4 : (z == 3) ? 2 : 3) * SZT;

  const int tid   = threadIdx.x;
  const int lane  = tid & 63;
  const int wid   = tid >> 6;
  const int wm    = wid >> 1, wn = wid & 1;
  const int colid = lane & 15, quad = lane >> 4;
  const int m0 = blockIdx.y * 128, n0 = blockIdx.x * 128;

  auto stage = [&](int kt, int pb) {
#pragma unroll
    for (int i = 0; i < 2; ++i) {
      const int slot = i * 256 + tid;        // 0..511, 16B each
      const int row = slot >> 2, ch = slot & 3;
      gld16(X + (m0 + row) * HDIM + kt + ch * 8, &Xs[pb][slot * 8]);
      gld16(W + (n0 + row) * HDIM + kt + ch * 8, &Ys[pb][slot * 8]);
    }
  };

  fx4 acc[4][4];
#pragma unroll
  for (int i = 0; i < 4; ++i)
#pragma unroll
    for (int j = 0; j < 4; ++j) acc[i][j] = (fx4){0.f, 0.f, 0.f, 0.f};

  stage(0, 0);
  __syncthreads();

  for (int it = 0; it < 24; ++it) {
    const int pb = it & 1;
    if (it + 1 < 24) stage((it + 1) * 32, pb ^ 1);

    bf8 af[4], bfr[4];
#pragma unroll
    for (int i = 0; i < 4; ++i)
      af[i] = *(const bf8*)&Xs[pb][(wm * 64 + i * 16 + colid) * 32 + quad * 8];
#pragma unroll
    for (int j = 0; j < 4; ++j)
      bfr[j] = *(const bf8*)&Ys[pb][(wn * 64 + j * 16 + colid) * 32 + quad * 8];
#pragma unroll
    for (int i = 0; i < 4; ++i)
#pragma unroll
      for (int j = 0; j < 4; ++j)
        acc[i][j] = __builtin_amdgcn_mfma_f32_16x16x32_bf16(af[i], bfr[j], acc[i][j], 0, 0, 0);
    __syncthreads();   // waves done with buf pb; staging pb^1 drained (vmcnt0)
  }

  // Epilogue. C/D layout: col=lane&15, row=quad*4+reg.
  if (z != 2) {
#pragma unroll
    for (int i = 0; i < 4; ++i) {
      const int r0 = m0 + wm * 64 + i * 16 + quad * 4;
      const int bb = r0 >> 10, s0 = r0 & 1023;
#pragma unroll
      for (int j = 0; j < 4; ++j) {
        const int c = n0 + wn * 64 + j * 16 + colid;
        const int h = c >> 6, d = c & 63;
        const float bvl = bias[c];
        unsigned short* op = out + (((bb * NHEADS + h) * SEQ + s0) * DHEAD + d);
#pragma unroll
        for (int reg = 0; reg < 4; ++reg)
          op[reg * DHEAD] = f2bf(acc[i][j][reg] + bvl);
      }
    }
  } else {
    // V -> f16, transposed: Vt[(bh*64+d)*1024 + s], 4 consecutive s per 8B store.
#pragma unroll
    for (int i = 0; i < 4; ++i) {
      const int r0 = m0 + wm * 64 + i * 16 + quad * 4;
      const int bb = r0 >> 10, s0 = r0 & 1023;
#pragma unroll
      for (int j = 0; j < 4; ++j) {
        const int c = n0 + wn * 64 + j * 16 + colid;
        const int h = c >> 6, d = c & 63;
        const float bvl = bias[c];
        h4 pk;
#pragma unroll
        for (int reg = 0; reg < 4; ++reg)
          pk[reg] = (_Float16)(acc[i][j][reg] + bvl);
        *(h4*)(void*)(out + ((size_t)((bb * NHEADS + h) * DHEAD + d)) * SEQ + s0) = pk;
      }
    }
  }
}

// ---------------------------------------------------------------------------
// Flash attention: block = (head, 64 q rows), 4 waves x 16 q, full 1024 keys.
// K/T/S tiles (64 keys) double-buffered in LDS via global_load_lds with one
// barrier per tile (prefetch overlaps compute). Transposed scores (C[key][q])
// => per-lane softmax (2 shfl), P regs feed 16x16x16_f16 PV directly.
// V + mask read from global at iteration top (L1/L2-hit, issued early).
// LDS chunks padded +32B/KB => conflict-free ds_read_b128 frag reads.
// ---------------------------------------------------------------------------
__global__ __launch_bounds__(256, 3)
void attn_kernel(const unsigned short* __restrict__ ws,
                 const float* __restrict__ maskb,
                 float* __restrict__ outb)
{
  __shared__ unsigned short KTS[2][3][8 * 528];   // 2 bufs x {K,T,S} x 8 chunks x (512+16) elems

  const unsigned short* Qb = ws;
  const unsigned short* GT0 = ws + (size_t)1 * SZT;   // K
  const unsigned short* GT1 = ws + (size_t)2 * SZT;   // T
  const unsigned short* GT2 = ws + (size_t)3 * SZT;   // S
  const _Float16* Vtf = (const _Float16*)(ws + (size_t)4 * SZT);

  const int tid   = threadIdx.x;
  const int lane  = tid & 63;
  const int w     = tid >> 6;
  const int colid = lane & 15, quad = lane >> 4;
  const int bh = blockIdx.y;
  const int b  = bh / NHEADS, h = bh % NHEADS;
  const int q0 = blockIdx.x * 64 + w * 16;
  const int base_h = bh * SEQ * DHEAD;

  // Invariant query-side B-frags: lane holds B[k=quad*8+j][n=colid] = Q[q0+colid][d]
  bf8 bqf[2], btf[2], bsf[2];
  {
    const int row = q0 + colid;
    const unsigned short* qp = Qb  + base_h + row * 64 + quad * 8;
    const unsigned short* tp = GT1 + base_h + row * 64 + quad * 8;
    const unsigned short* sp = GT2 + base_h + row * 64 + quad * 8;
    bqf[0] = *(const bf8*)qp;  bqf[1] = *(const bf8*)(qp + 32);
    btf[0] = *(const bf8*)tp;  btf[1] = *(const bf8*)(tp + 32);
    bsf[0] = *(const bf8*)sp;  bsf[1] = *(const bf8*)(sp + 32);
  }

  // Fused per-query scale: rs = 1/((|T_q|+eps)(|S_q|+eps)*8), for q = colid.
  float rs;
  {
    float t2 = 0.f, s2 = 0.f;
#pragma unroll
    for (int fr = 0; fr < 2; ++fr)
#pragma unroll
      for (int j = 0; j < 8; ++j) {
        const float tv = bf2f((unsigned short)btf[fr][j]);
        const float sv2 = bf2f((unsigned short)bsf[fr][j]);
        t2 += tv * tv; s2 += sv2 * sv2;
      }
    t2 += __shfl_xor(t2, 16); t2 += __shfl_xor(t2, 32);
    s2 += __shfl_xor(s2, 16); s2 += __shfl_xor(s2, 32);
    rs = 1.0f / ((sqrtf(t2) + EPSN) * (sqrtf(s2) + EPSN) * 8.0f);
  }

  // Cooperative K/T/S tile staging: 24 x 1KB chunks, 6 per wave.
  // Chunk sub covers keys sub*8..sub*8+7 (rows of 128B); lane: row=lane>>3, 16B col=lane&7.
  auto stageK = [&](int kb, int pb) {
#pragma unroll
    for (int i = 0; i < 6; ++i) {
      const int ch = w * 6 + i;
      const int tn = ch >> 3, sub = ch & 7;
      const unsigned short* g = (tn == 0 ? GT0 : tn == 1 ? GT1 : GT2)
                                + base_h + (kb + sub * 8 + (lane >> 3)) * 64 + (lane & 7) * 8;
      gld16(g, &KTS[pb][tn][sub * 528 + lane * 8]);
    }
  };

  float m_ = -1.0e30f, l_ = 0.f;
  fx4 o[4];
#pragma unroll
  for (int fd = 0; fd < 4; ++fd) o[fd] = (fx4){0.f, 0.f, 0.f, 0.f};
  const fx4 zero = (fx4){0.f, 0.f, 0.f, 0.f};

  stageK(0, 0);
  __syncthreads();

  for (int t = 0; t < 16; ++t) {
    const int pb = t & 1;
    const int kb = t * 64;

    // Early global loads for this tile (consumed after softmax, ~500 cyc later).
    h4 vv[4][4];
#pragma unroll
    for (int f = 0; f < 4; ++f)
#pragma unroll
      for (int fd = 0; fd < 4; ++fd)
        vv[f][fd] = *(const h4*)(Vtf + (size_t)(bh * DHEAD + fd * 16 + colid) * SEQ
                                     + kb + f * 16 + quad * 4);
    fx4 mk[4];
#pragma unroll
    for (int f = 0; f < 4; ++f)
      mk[f] = *(const fx4*)(maskb + b * SEQ + kb + f * 16 + quad * 4);

    // Prefetch next tile into the other buffer (drained by end-of-iter barrier).
    if (t + 1 < 16) stageK(kb + 64, pb ^ 1);

    // scores^T: A = K/T/S key rows from LDS, B = query regs. C[key=quad*4+reg][q=colid].
    float sv[4][4];
#pragma unroll
    for (int f = 0; f < 4; ++f) {
      // row = f*16+colid -> chunk f*2+(colid>>3), in-chunk row colid&7, halves at +32.
      const int coff = (f * 2 + (colid >> 3)) * 528 + (colid & 7) * 64 + quad * 8;
      const bf8 ak0 = *(const bf8*)&KTS[pb][0][coff];
      const bf8 ak1 = *(const bf8*)&KTS[pb][0][coff + 32];
      const bf8 at0 = *(const bf8*)&KTS[pb][1][coff];
      const bf8 at1 = *(const bf8*)&KTS[pb][1][coff + 32];
      const bf8 as0 = *(const bf8*)&KTS[pb][2][coff];
      const bf8 as1 = *(const bf8*)&KTS[pb][2][coff + 32];
      fx4 ab = __builtin_amdgcn_mfma_f32_16x16x32_bf16(ak0, bqf[0], zero, 0, 0, 0);
      ab = __builtin_amdgcn_mfma_f32_16x16x32_bf16(ak1, bqf[1], ab, 0, 0, 0);
      fx4 tt = __builtin_amdgcn_mfma_f32_16x16x32_bf16(at0, btf[0], zero, 0, 0, 0);
      tt = __builtin_amdgcn_mfma_f32_16x16x32_bf16(at1, btf[1], tt, 0, 0, 0);
      fx4 ss = __builtin_amdgcn_mfma_f32_16x16x32_bf16(as0, bsf[0], zero, 0, 0, 0);
      ss = __builtin_amdgcn_mfma_f32_16x16x32_bf16(as1, bsf[1], ss, 0, 0, 0);
#pragma unroll
      for (int reg = 0; reg < 4; ++reg)
        sv[f][reg] = (ab[reg] * tt[reg]) * ss[reg] * rs + mk[f][reg];
    }

    // Per-lane softmax for q=colid (16 in-lane scores + 2-shfl cross-quad reduce).
    float bm = sv[0][0];
#pragma unroll
    for (int f = 0; f < 4; ++f)
#pragma unroll
      for (int reg = 0; reg < 4; ++reg) bm = fmaxf(bm, sv[f][reg]);
    bm = fmaxf(bm, __shfl_xor(bm, 16));
    bm = fmaxf(bm, __shfl_xor(bm, 32));
    const float mn = fmaxf(m_, bm);
    const float alpha = __expf(m_ - mn);
    float rsum = 0.f;
    h4 pa[4];
#pragma unroll
    for (int f = 0; f < 4; ++f)
#pragma unroll
      for (int reg = 0; reg < 4; ++reg) {
        const float p = __expf(sv[f][reg] - mn);
        rsum += p;
        pa[f][reg] = (_Float16)p;
      }
    rsum += __shfl_xor(rsum, 16);
    rsum += __shfl_xor(rsum, 32);
    l_ = l_ * alpha + rsum;
    m_ = mn;

    // O rows are q=quad*4+reg: fetch their alpha from the lane with colid==row.
    float ar[4];
#pragma unroll
    for (int reg = 0; reg < 4; ++reg) ar[reg] = __shfl(alpha, quad * 4 + reg);
#pragma unroll
    for (int fd = 0; fd < 4; ++fd)
#pragma unroll
      for (int reg = 0; reg < 4; ++reg) o[fd][reg] *= ar[reg];

    // O += P.V : P regs are the 16x16x16 A-frag (m=q=colid, k=quad*4+reg).
#pragma unroll
    for (int f = 0; f < 4; ++f)
#pragma unroll
      for (int fd = 0; fd < 4; ++fd)
        o[fd] = __builtin_amdgcn_mfma_f32_16x16x16f16(pa[f], vv[f][fd], o[fd], 0, 0, 0);

    __syncthreads();   // all waves done reading buf pb; staging of pb^1 drained
  }

  // Epilogue: out[b, s, h*64+d] = O / l  (f32 out). O rows q=quad*4+reg, col d=fd*16+colid.
  const float linv = 1.0f / l_;                 // valid per q=colid
  float ir[4];
#pragma unroll
  for (int reg = 0; reg < 4; ++reg) ir[reg] = __shfl(linv, quad * 4 + reg);
#pragma unroll
  for (int reg = 0; reg < 4; ++reg) {
    const int s = q0 + quad * 4 + reg;
#pragma unroll
    for (int fd = 0; fd < 4; ++fd)
      outb[(size_t)(b * SEQ + s) * HDIM + h * DHEAD + fd * 16 + colid] = o[fd][reg] * ir[reg];
  }
}

extern "C" void kernel_launch(void* const* d_in, const int* in_sizes, int n_in,
                              void* d_out, int out_size, void* d_ws, size_t ws_size,
                              hipStream_t stream)
{
  (void)in_sizes; (void)n_in; (void)out_size; (void)ws_size;
  const float* hs   = (const float*)d_in[0];
  const float* te   = (const float*)d_in[1];
  const float* se   = (const float*)d_in[2];
  const float* mask = (const float*)d_in[3];
  const float* Wq   = (const float*)d_in[4];
  const float* bq   = (const float*)d_in[5];
  const float* Wk   = (const float*)d_in[6];
  const float* bk   = (const float*)d_in[7];
  const float* Wv   = (const float*)d_in[8];
  const float* bv   = (const float*)d_in[9];
  const float* Wt   = (const float*)d_in[10];
  const float* bt   = (const float*)d_in[11];
  const float* Wsp  = (const float*)d_in[12];
  const float* bsp  = (const float*)d_in[13];
  float* out = (float*)d_out;
  unsigned short* ws = (unsigned short*)d_ws;

  // ws layout (ushort units): Qb@0 Kb@1SZ Tb@2SZ Sb@3SZ Vt(f16)@4SZ
  // convert-phase: hsb@5SZ teb@6SZ seb@7SZ W[5]@8SZ+z*589824 (dead after proj)
  convert_kernel<<<dim3(1536, 8), 256, 0, stream>>>(hs, te, se, Wq, Wk, Wv, Wt, Wsp, ws);
  proj_kernel<<<dim3(6, 32, 5), 256, 0, stream>>>(ws, bq, bk, bv, bt, bsp);
  attn_kernel<<<dim3(16, BH_TOT), 256, 0, stream>>>(ws, mask, out);
}